// Round 12
// baseline (415.908 us; speedup 1.0000x reference)
//
#include <hip/hip_runtime.h>
#include <math.h>

#define BATCH 256
#define QL 50
#define EMB 50
#define DL 2000
#define NB 11
#define SEG 16
#define RPB 125      // d rows per block (DL/SEG)
#define TPB 256
#define RSTRIDE 52   // LDS row stride in floats: 208 B = 13*16 -> float4-aligned rows
#define HB (QL * NB) // 550

// ---- 5x5 register tile macros ----
#define FOR_M5(M) M(0) M(1) M(2) M(3) M(4)
#define FOR_MN(M) \
  M(0,0) M(0,1) M(0,2) M(0,3) M(0,4) \
  M(1,0) M(1,1) M(1,2) M(1,3) M(1,4) \
  M(2,0) M(2,1) M(2,2) M(2,3) M(2,4) \
  M(3,0) M(3,1) M(3,2) M(3,3) M(3,4) \
  M(4,0) M(4,1) M(4,2) M(4,3) M(4,4)

#define DECL_ACC(m,n) float a_##m##_##n = 0.f;

// A/B double-buffered LDS->reg loads (software pipeline, depth 1)
#define DECL_BUF \
  float4 qA0,qA1,qA2,qA3,qA4,dA0,dA1,dA2,dA3,dA4; \
  float4 qB0,qB1,qB2,qB3,qB4,dB0,dB1,dB2,dB3,dB4;
#define LDA_Q(m) qA##m = *(const float4*)(qb0 + (m) * RSTRIDE + o);
#define LDA_D(n) dA##n = *(const float4*)(db0 + (n) * RSTRIDE + o);
#define LDB_Q(m) qB##m = *(const float4*)(qb0 + (m) * RSTRIDE + o);
#define LDB_D(n) dB##n = *(const float4*)(db0 + (n) * RSTRIDE + o);
#define LOADA(oo) { const int o = (oo); FOR_M5(LDA_Q) FOR_M5(LDA_D) }
#define LOADB(oo) { const int o = (oo); FOR_M5(LDB_Q) FOR_M5(LDB_D) }

// e-ascending exact chain: each FMA block is one k (4 floats), k ascending
#define FMAA(m,n) \
  a_##m##_##n = fmaf(qA##m.x, dA##n.x, a_##m##_##n); \
  a_##m##_##n = fmaf(qA##m.y, dA##n.y, a_##m##_##n); \
  a_##m##_##n = fmaf(qA##m.z, dA##n.z, a_##m##_##n); \
  a_##m##_##n = fmaf(qA##m.w, dA##n.w, a_##m##_##n);
#define FMAB(m,n) \
  a_##m##_##n = fmaf(qB##m.x, dB##n.x, a_##m##_##n); \
  a_##m##_##n = fmaf(qB##m.y, dB##n.y, a_##m##_##n); \
  a_##m##_##n = fmaf(qB##m.z, dB##n.z, a_##m##_##n); \
  a_##m##_##n = fmaf(qB##m.w, dB##n.w, a_##m##_##n);

#define LQ2(m) const float2 qt##m = *(const float2*)(qb0 + (m) * RSTRIDE + 48);
#define LD2(n) const float2 dt##n = *(const float2*)(db0 + (n) * RSTRIDE + 48);
#define FMA2T(m,n) \
  a_##m##_##n = fmaf(qt##m.x, dt##n.x, a_##m##_##n); \
  a_##m##_##n = fmaf(qt##m.y, dt##n.y, a_##m##_##n);

// binning verbatim from all passing rounds: ((a*qrn)*drn), trunc, clamp
#define HIST_MN(m,n) if (qv_##m && dv_##n) { \
    const float s_  = a_##m##_##n * qrn##m * drn##n; \
    const float tt_ = ((s_ + 1.000001f) * 0.5f) * 10.0f; \
    int bb_ = (int)tt_; bb_ = bb_ < 0 ? 0 : (bb_ > 10 ? 10 : bb_); \
    atomicAdd(&s_hist[(qg5 + m) * NB + bb_], 1u); }

// ---------------- sim+hist (+gate on seg==0) ----------------
__global__ __launch_bounds__(TPB, 4)
void sim_hist_kernel(const float* __restrict__ de,
                     const int*   __restrict__ did,
                     const float* __restrict__ qe,
                     const int*   __restrict__ qid,
                     const float* __restrict__ Wg,
                     unsigned char* __restrict__ g_hist, // [B][SEG][HB]
                     float* __restrict__ gate,
                     int* __restrict__ cnt)
{
    const int bid = blockIdx.x;
    const int b   = bid >> 4;
    const int seg = bid & 15;
    const int t   = threadIdx.x;

    __shared__ __align__(16) float s_d[RPB * RSTRIDE]; // 26,000 B row-major
    __shared__ __align__(16) float s_q[QL * RSTRIDE];  // 10,400 B row-major
    __shared__ float         s_drn[RPB];
    __shared__ float         s_qrn[QL];
    __shared__ unsigned char s_dval[RPB];
    __shared__ unsigned char s_qv[QL];
    __shared__ unsigned      s_hist[HB];
    __shared__ float         r2s[4];

    if (bid == 0 && t == 0) *cnt = 0;      // re-arm epilogue flag each launch
    for (int i = t; i < HB; i += TPB) s_hist[i] = 0u;

    // ---- fused stage + norm, one phase one barrier (R9 verbatim) ----
    if (t < RPB) {
        const float* src = de + ((size_t)b * DL + seg * RPB + t) * EMB;
        float* dst = s_d + t * RSTRIDE;
        float ss = 0.f;
        #pragma unroll
        for (int ep = 0; ep < 25; ++ep) {
            const float2 v = *(const float2*)(src + 2 * ep);
            ss = fmaf(v.x, v.x, ss);
            ss = fmaf(v.y, v.y, ss);
            *(float2*)(dst + 2 * ep) = v;
        }
        s_drn[t]  = 1.0f / (sqrtf(ss) + 1e-8f);
        s_dval[t] = (did[(size_t)b * DL + seg * RPB + t] > 0) ? 1 : 0;
    } else if (t >= 128 && t < 128 + QL) {
        const int j = t - 128;
        const float* src = qe + ((size_t)b * QL + j) * EMB;
        float* dst = s_q + j * RSTRIDE;
        float ss = 0.f;
        #pragma unroll
        for (int ep = 0; ep < 25; ++ep) {
            const float2 v = *(const float2*)(src + 2 * ep);
            ss = fmaf(v.x, v.x, ss);
            ss = fmaf(v.y, v.y, ss);
            *(float2*)(dst + 2 * ep) = v;
        }
        s_qrn[j] = 1.0f / (sqrtf(ss) + 1e-8f);
        s_qv[j]  = (qid[(size_t)b * QL + j] > 0) ? 1 : 0;
    }
    __syncthreads();

    // ---- 5x5 register-tiled dots, software-pipelined b128 LDS reads ----
    if (t < 250) {
        const int qg5 = (t % 10) * 5;      // adjacent lanes -> different q group
        const int rg5 = (t / 10) * 5;
        const float* qb0 = s_q + qg5 * RSTRIDE;
        const float* db0 = s_d + rg5 * RSTRIDE;
        FOR_MN(DECL_ACC)
        DECL_BUF
        LOADA(0)                           // k=0
        #pragma unroll 1
        for (int kk = 0; kk < 5; ++kk) {   // covers k=0..9, loads k=1..10
            LOADB(4 * (2 * kk + 1));
            FOR_MN(FMAA)                   // k = 2kk
            LOADA(4 * (2 * kk + 2));
            FOR_MN(FMAB)                   // k = 2kk+1
        }
        LOADB(44);
        FOR_MN(FMAA)                       // k = 10
        FOR_MN(FMAB)                       // k = 11
        {                                  // tail e = 48,49
            FOR_M5(LQ2)
            FOR_M5(LD2)
            FOR_MN(FMA2T)
        }
        const float qrn0 = s_qrn[qg5+0], qrn1 = s_qrn[qg5+1], qrn2 = s_qrn[qg5+2],
                    qrn3 = s_qrn[qg5+3], qrn4 = s_qrn[qg5+4];
        const float drn0 = s_drn[rg5+0], drn1 = s_drn[rg5+1], drn2 = s_drn[rg5+2],
                    drn3 = s_drn[rg5+3], drn4 = s_drn[rg5+4];
        const int qv_0 = s_qv[qg5+0], qv_1 = s_qv[qg5+1], qv_2 = s_qv[qg5+2],
                  qv_3 = s_qv[qg5+3], qv_4 = s_qv[qg5+4];
        const int dv_0 = s_dval[rg5+0], dv_1 = s_dval[rg5+1], dv_2 = s_dval[rg5+2],
                  dv_3 = s_dval[rg5+3], dv_4 = s_dval[rg5+4];
        FOR_MN(HIST_MN)                    // 25 LDS atomics, lane-staggered q
    }
    __syncthreads();

    // ---- flush block-private u8 histogram (max count 125 < 256) ----
    unsigned char* hout = g_hist + ((size_t)b * SEG + seg) * HB;
    for (int i = t; i < HB; i += TPB) hout[i] = (unsigned char)s_hist[i];

    // ---- gate dot (seg==0 only; verbatim exact code) ----
    if (seg == 0) {
        const float* qbase = qe + (size_t)b * QL * EMB;
        float a2 = 0.f;
        for (int i = t; i < QL * EMB; i += TPB)
            a2 = fmaf(qbase[i], Wg[i], a2);
        #pragma unroll
        for (int off = 32; off > 0; off >>= 1) a2 += __shfl_down(a2, off, 64);
        if ((t & 63) == 0) r2s[t >> 6] = a2;
        __syncthreads();
        if (t == 0) gate[b] = r2s[0] + r2s[1] + r2s[2] + r2s[3];
    }
}

// ---------------- ffn + (last block) softmax/score (R9 verbatim) ----------------
__global__ __launch_bounds__(TPB)
void ffn_score_kernel(const unsigned char* __restrict__ g_hist,
                      const float* __restrict__ W1,
                      const float* __restrict__ bias,
                      const float* __restrict__ gate,
                      float* __restrict__ ffn,
                      int* __restrict__ cnt,
                      float* __restrict__ out)
{
    const int b = blockIdx.x;
    const int t = threadIdx.x;
    const unsigned char* hb = g_hist + (size_t)b * SEG * HB;

    float a1 = 0.f;
    for (int i = t; i < HB; i += TPB) {
        unsigned c = 0;
        #pragma unroll
        for (int s = 0; s < SEG; ++s) c += hb[s * HB + i];  // integer: exact
        a1 = fmaf(logf((float)c + 1e-5f), W1[i], a1);
    }
    #pragma unroll
    for (int off = 32; off > 0; off >>= 1) a1 += __shfl_down(a1, off, 64);
    __shared__ float r1s[4];
    __shared__ int   s_last;
    if ((t & 63) == 0) r1s[t >> 6] = a1;
    __syncthreads();
    if (t == 0) {
        const float v = r1s[0] + r1s[1] + r1s[2] + r1s[3] + bias[0];
        atomicExch(&ffn[b], v);            // device-coherent publish
        __threadfence();
        const int old = atomicAdd(cnt, 1);
        s_last = (old == BATCH - 1) ? 1 : 0;
    }
    __syncthreads();
    if (!s_last) return;
    __threadfence();

    // ---- score: verbatim exact softmax-over-batch path ----
    __shared__ float buf[4];
    __shared__ float sM, sZ, sS;
    const float g = gate[t];
    const float f = atomicAdd(&ffn[t], 0.0f);      // device-coherent read

    float m = g;
    #pragma unroll
    for (int off = 32; off > 0; off >>= 1) m = fmaxf(m, __shfl_down(m, off, 64));
    if ((t & 63) == 0) buf[t >> 6] = m;
    __syncthreads();
    if (t == 0) sM = fmaxf(fmaxf(buf[0], buf[1]), fmaxf(buf[2], buf[3]));
    __syncthreads();

    const float e = expf(g - sM);
    float z = e;
    #pragma unroll
    for (int off = 32; off > 0; off >>= 1) z += __shfl_down(z, off, 64);
    __syncthreads();
    if ((t & 63) == 0) buf[t >> 6] = z;
    __syncthreads();
    if (t == 0) sZ = buf[0] + buf[1] + buf[2] + buf[3];
    __syncthreads();

    const float p = e / sZ;
    float s = p;
    #pragma unroll
    for (int off = 32; off > 0; off >>= 1) s += __shfl_down(s, off, 64);
    __syncthreads();
    if ((t & 63) == 0) buf[t >> 6] = s;
    __syncthreads();
    if (t == 0) sS = buf[0] + buf[1] + buf[2] + buf[3];
    __syncthreads();

    out[t] = f * sS;
}

// ---------------- launcher: 2 dispatches ----------------
extern "C" void kernel_launch(void* const* d_in, const int* in_sizes, int n_in,
                              void* d_out, int out_size, void* d_ws, size_t ws_size,
                              hipStream_t stream)
{
    const float* qe  = (const float*)d_in[0];
    const float* de  = (const float*)d_in[1];
    const float* W1  = (const float*)d_in[2];
    const float* b1  = (const float*)d_in[3];
    const float* Wg  = (const float*)d_in[4];
    const int*   qid = (const int*)d_in[5];
    const int*   did = (const int*)d_in[6];
    float* out = (float*)d_out;

    // workspace (~2.26 MB)
    char* ws = (char*)d_ws;
    unsigned char* g_hist = (unsigned char*)ws;        // 256*16*550 = 2,252,800 B
    float* gate = (float*)(ws + 2252800);              // 1,024 B
    float* ffn  = gate + BATCH;                        // 1,024 B
    int*   cnt  = (int*)(ffn + BATCH);                 // 4 B

    sim_hist_kernel<<<BATCH * SEG, TPB, 0, stream>>>(de, did, qe, qid, Wg,
                                                     g_hist, gate, cnt);
    ffn_score_kernel<<<BATCH, TPB, 0, stream>>>(g_hist, W1, b1, gate, ffn, cnt, out);
}

// Round 13
// 231.753 us; speedup vs baseline: 1.7946x; 1.7946x over previous
//
#include <hip/hip_runtime.h>
#include <math.h>

#define BATCH 256
#define QL 50
#define EMB 50
#define DL 2000
#define NB 11
#define SEG 16
#define RPB 125      // d rows per block (DL/SEG)
#define TPB 256
#define RSTRIDE 52   // LDS row stride in floats: 208 B = 13*16 -> float4-aligned rows
#define HB (QL * NB) // 550

// ---- 5x5 register tile macros (R9 verbatim) ----
#define FOR_M5(M) M(0) M(1) M(2) M(3) M(4)
#define FOR_MN(M) \
  M(0,0) M(0,1) M(0,2) M(0,3) M(0,4) \
  M(1,0) M(1,1) M(1,2) M(1,3) M(1,4) \
  M(2,0) M(2,1) M(2,2) M(2,3) M(2,4) \
  M(3,0) M(3,1) M(3,2) M(3,3) M(3,4) \
  M(4,0) M(4,1) M(4,2) M(4,3) M(4,4)

#define DECL_ACC(m,n) float a_##m##_##n = 0.f;
#define LOAD_Q4(m) const float4 qv##m = *(const float4*)(qb0 + (m) * RSTRIDE + 4 * k);
#define LOAD_D4(n) const float4 dv##n = *(const float4*)(db0 + (n) * RSTRIDE + 4 * k);
#define LOAD_Q2(m) const float2 qt##m = *(const float2*)(qb0 + (m) * RSTRIDE + 48);
#define LOAD_D2(n) const float2 dt##n = *(const float2*)(db0 + (n) * RSTRIDE + 48);
// e-ascending exact chain: quads k=0..11 cover e=0..47, then tail e=48,49
#define FMA4(m,n) \
  a_##m##_##n = fmaf(qv##m.x, dv##n.x, a_##m##_##n); \
  a_##m##_##n = fmaf(qv##m.y, dv##n.y, a_##m##_##n); \
  a_##m##_##n = fmaf(qv##m.z, dv##n.z, a_##m##_##n); \
  a_##m##_##n = fmaf(qv##m.w, dv##n.w, a_##m##_##n);
#define FMA2T(m,n) \
  a_##m##_##n = fmaf(qt##m.x, dt##n.x, a_##m##_##n); \
  a_##m##_##n = fmaf(qt##m.y, dt##n.y, a_##m##_##n);
// binning verbatim from all passing rounds: ((a*qrn)*drn), trunc, clamp
#define HIST_MN(m,n) if (qv_##m && dv_##n) { \
    const float s_  = a_##m##_##n * qrn##m * drn##n; \
    const float tt_ = ((s_ + 1.000001f) * 0.5f) * 10.0f; \
    int bb_ = (int)tt_; bb_ = bb_ < 0 ? 0 : (bb_ > 10 ? 10 : bb_); \
    atomicAdd(&s_hist[(qg5 + m) * NB + bb_], 1u); }

// ---------------- sim+hist (+gate on seg==0) ----------------
__global__ __launch_bounds__(TPB, 4)
void sim_hist_kernel(const float* __restrict__ de,
                     const int*   __restrict__ did,
                     const float* __restrict__ qe,
                     const int*   __restrict__ qid,
                     const float* __restrict__ Wg,
                     unsigned char* __restrict__ g_hist, // [B][SEG][HB]
                     float* __restrict__ gate,
                     int* __restrict__ cnt)
{
    const int bid = blockIdx.x;
    const int b   = bid >> 4;
    const int seg = bid & 15;
    const int t   = threadIdx.x;

    __shared__ __align__(16) float s_d[RPB * RSTRIDE]; // 26,000 B row-major
    __shared__ __align__(16) float s_q[QL * RSTRIDE];  // 10,400 B row-major
    __shared__ float         s_drn[RPB];
    __shared__ float         s_qrn[QL];
    __shared__ unsigned char s_dval[RPB];
    __shared__ unsigned char s_qv[QL];
    __shared__ unsigned      s_hist[HB];
    __shared__ float         r2s[4];

    if (bid == 0 && t == 0) *cnt = 0;      // re-arm epilogue flag each launch
    for (int i = t; i < HB; i += TPB) s_hist[i] = 0u;

    // ---- raster staging: conflict-free LDS writes, coalesced global reads ----
    const float2* dsrc = (const float2*)(de + ((size_t)b * DL + seg * RPB) * EMB);
    for (int i = t; i < RPB * 25; i += TPB) {
        const int r = i / 25, ep = i - r * 25;
        ((float2*)(s_d + r * RSTRIDE))[ep] = dsrc[i];
    }
    const float2* qsrc = (const float2*)(qe + (size_t)b * QL * EMB);
    for (int i = t; i < QL * 25; i += TPB) {
        const int r = i / 25, ep = i - r * 25;
        ((float2*)(s_q + r * RSTRIDE))[ep] = qsrc[i];
    }

    // ---- norms from GLOBAL (L1/L2-hot; off the LDS pipe), exact chains ----
    if (t < RPB) {
        const float* src = de + ((size_t)b * DL + seg * RPB + t) * EMB;
        float ss = 0.f;
        #pragma unroll
        for (int ep = 0; ep < 25; ++ep) {
            const float2 v = *(const float2*)(src + 2 * ep);
            ss = fmaf(v.x, v.x, ss);
            ss = fmaf(v.y, v.y, ss);
        }
        s_drn[t]  = 1.0f / (sqrtf(ss) + 1e-8f);
        s_dval[t] = (did[(size_t)b * DL + seg * RPB + t] > 0) ? 1 : 0;
    } else if (t >= 128 && t < 128 + QL) {
        const int j = t - 128;
        const float* src = qe + ((size_t)b * QL + j) * EMB;
        float ss = 0.f;
        #pragma unroll
        for (int ep = 0; ep < 25; ++ep) {
            const float2 v = *(const float2*)(src + 2 * ep);
            ss = fmaf(v.x, v.x, ss);
            ss = fmaf(v.y, v.y, ss);
        }
        s_qrn[j] = 1.0f / (sqrtf(ss) + 1e-8f);
        s_qv[j]  = (qid[(size_t)b * QL + j] > 0) ? 1 : 0;
    }
    __syncthreads();

    // ---- 5x5 register-tiled dot products, b128 LDS reads (R9 verbatim) ----
    if (t < 250) {
        const int qg5 = (t % 10) * 5;      // adjacent lanes -> different q group
        const int rg5 = (t / 10) * 5;
        const float* qb0 = s_q + qg5 * RSTRIDE;
        const float* db0 = s_d + rg5 * RSTRIDE;
        FOR_MN(DECL_ACC)
        #pragma unroll 1
        for (int k = 0; k < 12; ++k) {     // rolled: live set ~75 VGPR, no hoist
            FOR_M5(LOAD_Q4)
            FOR_M5(LOAD_D4)
            FOR_MN(FMA4)                   // 100 fmacs per 10 ds_read_b128
        }
        {                                  // tail e = 48,49
            FOR_M5(LOAD_Q2)
            FOR_M5(LOAD_D2)
            FOR_MN(FMA2T)
        }
        const float qrn0 = s_qrn[qg5+0], qrn1 = s_qrn[qg5+1], qrn2 = s_qrn[qg5+2],
                    qrn3 = s_qrn[qg5+3], qrn4 = s_qrn[qg5+4];
        const float drn0 = s_drn[rg5+0], drn1 = s_drn[rg5+1], drn2 = s_drn[rg5+2],
                    drn3 = s_drn[rg5+3], drn4 = s_drn[rg5+4];
        const int qv_0 = s_qv[qg5+0], qv_1 = s_qv[qg5+1], qv_2 = s_qv[qg5+2],
                  qv_3 = s_qv[qg5+3], qv_4 = s_qv[qg5+4];
        const int dv_0 = s_dval[rg5+0], dv_1 = s_dval[rg5+1], dv_2 = s_dval[rg5+2],
                  dv_3 = s_dval[rg5+3], dv_4 = s_dval[rg5+4];
        FOR_MN(HIST_MN)                    // 25 LDS atomics, lane-staggered q
    }
    __syncthreads();

    // ---- flush block-private u8 histogram (max count 125 < 256) ----
    unsigned char* hout = g_hist + ((size_t)b * SEG + seg) * HB;
    for (int i = t; i < HB; i += TPB) hout[i] = (unsigned char)s_hist[i];

    // ---- gate dot (seg==0 only; verbatim exact code) ----
    if (seg == 0) {
        const float* qbase = qe + (size_t)b * QL * EMB;
        float a2 = 0.f;
        for (int i = t; i < QL * EMB; i += TPB)
            a2 = fmaf(qbase[i], Wg[i], a2);
        #pragma unroll
        for (int off = 32; off > 0; off >>= 1) a2 += __shfl_down(a2, off, 64);
        if ((t & 63) == 0) r2s[t >> 6] = a2;
        __syncthreads();
        if (t == 0) gate[b] = r2s[0] + r2s[1] + r2s[2] + r2s[3];
    }
}

// ---------------- ffn + (last block) softmax/score (R9 verbatim) ----------------
__global__ __launch_bounds__(TPB)
void ffn_score_kernel(const unsigned char* __restrict__ g_hist,
                      const float* __restrict__ W1,
                      const float* __restrict__ bias,
                      const float* __restrict__ gate,
                      float* __restrict__ ffn,
                      int* __restrict__ cnt,
                      float* __restrict__ out)
{
    const int b = blockIdx.x;
    const int t = threadIdx.x;
    const unsigned char* hb = g_hist + (size_t)b * SEG * HB;

    float a1 = 0.f;
    for (int i = t; i < HB; i += TPB) {
        unsigned c = 0;
        #pragma unroll
        for (int s = 0; s < SEG; ++s) c += hb[s * HB + i];  // integer: exact
        a1 = fmaf(logf((float)c + 1e-5f), W1[i], a1);
    }
    #pragma unroll
    for (int off = 32; off > 0; off >>= 1) a1 += __shfl_down(a1, off, 64);
    __shared__ float r1s[4];
    __shared__ int   s_last;
    if ((t & 63) == 0) r1s[t >> 6] = a1;
    __syncthreads();
    if (t == 0) {
        const float v = r1s[0] + r1s[1] + r1s[2] + r1s[3] + bias[0];
        atomicExch(&ffn[b], v);            // device-coherent publish
        __threadfence();
        const int old = atomicAdd(cnt, 1);
        s_last = (old == BATCH - 1) ? 1 : 0;
    }
    __syncthreads();
    if (!s_last) return;
    __threadfence();

    // ---- score: verbatim exact softmax-over-batch path ----
    __shared__ float buf[4];
    __shared__ float sM, sZ, sS;
    const float g = gate[t];
    const float f = atomicAdd(&ffn[t], 0.0f);      // device-coherent read

    float m = g;
    #pragma unroll
    for (int off = 32; off > 0; off >>= 1) m = fmaxf(m, __shfl_down(m, off, 64));
    if ((t & 63) == 0) buf[t >> 6] = m;
    __syncthreads();
    if (t == 0) sM = fmaxf(fmaxf(buf[0], buf[1]), fmaxf(buf[2], buf[3]));
    __syncthreads();

    const float e = expf(g - sM);
    float z = e;
    #pragma unroll
    for (int off = 32; off > 0; off >>= 1) z += __shfl_down(z, off, 64);
    __syncthreads();
    if ((t & 63) == 0) buf[t >> 6] = z;
    __syncthreads();
    if (t == 0) sZ = buf[0] + buf[1] + buf[2] + buf[3];
    __syncthreads();

    const float p = e / sZ;
    float s = p;
    #pragma unroll
    for (int off = 32; off > 0; off >>= 1) s += __shfl_down(s, off, 64);
    __syncthreads();
    if ((t & 63) == 0) buf[t >> 6] = s;
    __syncthreads();
    if (t == 0) sS = buf[0] + buf[1] + buf[2] + buf[3];
    __syncthreads();

    out[t] = f * sS;
}

// ---------------- launcher: 2 dispatches ----------------
extern "C" void kernel_launch(void* const* d_in, const int* in_sizes, int n_in,
                              void* d_out, int out_size, void* d_ws, size_t ws_size,
                              hipStream_t stream)
{
    const float* qe  = (const float*)d_in[0];
    const float* de  = (const float*)d_in[1];
    const float* W1  = (const float*)d_in[2];
    const float* b1  = (const float*)d_in[3];
    const float* Wg  = (const float*)d_in[4];
    const int*   qid = (const int*)d_in[5];
    const int*   did = (const int*)d_in[6];
    float* out = (float*)d_out;

    // workspace (~2.26 MB)
    char* ws = (char*)d_ws;
    unsigned char* g_hist = (unsigned char*)ws;        // 256*16*550 = 2,252,800 B
    float* gate = (float*)(ws + 2252800);              // 1,024 B
    float* ffn  = gate + BATCH;                        // 1,024 B
    int*   cnt  = (int*)(ffn + BATCH);                 // 4 B

    sim_hist_kernel<<<BATCH * SEG, TPB, 0, stream>>>(de, did, qe, qid, Wg,
                                                     g_hist, gate, cnt);
    ffn_score_kernel<<<BATCH, TPB, 0, stream>>>(g_hist, W1, b1, gate, ffn, cnt, out);
}